// Round 12
// baseline (172.676 us; speedup 1.0000x reference)
//
#include <hip/hip_runtime.h>
#include <hip/hip_bf16.h>

// DiffAttn: B=4, S=4096, EMB=1024, D=128
//   Q = X@Wq+bq (256 cols = Q1|Q2), K likewise, V = X@Wv+bv (128)
//   out = softmax(Q1K1^T/sqrt(D))@V - lam*softmax(Q2K2^T/sqrt(D))@V
// R12: attn reverted to the R8-verified kernel (115.5 us). This round
// optimizes the non-attn tail: xcvt (X->bf16 once, aliases Po), proj2
// (all-bf16 GEMM, global_load_lds staging, BK=64 dbuf, MFMA32), vtrans2
// (LDS-tiled coalesced transpose).

typedef __attribute__((ext_vector_type(8))) short bf16x8;    // 8 bf16
typedef __attribute__((ext_vector_type(4))) float f32x4;
typedef __attribute__((ext_vector_type(16))) float f32x16;   // 32x32 C/D

#define MFMA16(a, b, c) __builtin_amdgcn_mfma_f32_16x16x32_bf16((a), (b), (c), 0, 0, 0)
#define MFMA32(a, b, c) __builtin_amdgcn_mfma_f32_32x32x16_bf16((a), (b), (c), 0, 0, 0)

typedef const __attribute__((address_space(1))) void gas_void;
typedef __attribute__((address_space(3))) void las_void;
#define GLOAD16(G, L) __builtin_amdgcn_global_load_lds((gas_void*)(G), (las_void*)(L), 16, 0, 0)

__device__ __forceinline__ unsigned short f2bf(float x) {
    union { float f; unsigned u; } v; v.f = x;   // RNE float->bf16
    return (unsigned short)((v.u + 0x7FFFu + ((v.u >> 16) & 1u)) >> 16);
}
__device__ __forceinline__ unsigned pk2bf(float a, float b) {   // v_cvt_pk_bf16_f32
    __hip_bfloat162 h = __float22bfloat162_rn(float2{a, b});
    union { __hip_bfloat162 h2; unsigned u; } cv; cv.h2 = h;
    return cv.u;
}
__device__ __forceinline__ float fexp2(float x) {   // raw v_exp_f32: D = 2^S0
    float r; asm("v_exp_f32 %0, %1" : "=v"(r) : "v"(x)); return r;
}

// ---------------- W transpose + bf16 convert: Wt[640][1024] ----------------
__global__ __launch_bounds__(256) void wtrans_kernel(
    const float* __restrict__ Wq, const float* __restrict__ Wk,
    const float* __restrict__ Wv, unsigned short* __restrict__ Wt) {
    int tid = blockIdx.x * 256 + threadIdx.x;   // 640*1024 total
    int k = tid & 1023, n = tid >> 10;
    float v;
    if (n < 256)      v = Wq[k * 256 + n];
    else if (n < 512) v = Wk[k * 256 + (n - 256)];
    else              v = Wv[k * 128 + (n - 512)];
    Wt[tid] = f2bf(v);
}

// ---------------- X -> bf16: Xb[16384][1024] ----------------
__global__ __launch_bounds__(256) void xcvt_kernel(
    const float* __restrict__ X, unsigned short* __restrict__ Xb) {
    long i = ((long)blockIdx.x * 256 + threadIdx.x) * 8;
    float4 a = *(const float4*)(X + i);
    float4 b = *(const float4*)(X + i + 4);
    uint4 u;
    u.x = pk2bf(a.x, a.y); u.y = pk2bf(a.z, a.w);
    u.z = pk2bf(b.x, b.y); u.w = pk2bf(b.z, b.w);
    *(uint4*)(Xb + i) = u;
}

// ---------------- QKV projection GEMM v2 (all-bf16, gload_lds) ------------
// grid (128, 5): y = 0,1 -> Q (scaled); 2,3 -> K; 4 -> V. 256 thr = 4 waves
// (wm,wn in 2x2), each wave 64x64 out = acc[2][2] of 32x32. BK=64, 2-buf.
// LDS per buf: A[128][128B rot] @0 (16K) | B[128][128B rot] @16384.
__global__ __launch_bounds__(256) void proj2_kernel(
    const unsigned short* __restrict__ Xb, const unsigned short* __restrict__ Wt,
    const float* __restrict__ bq, const float* __restrict__ bk,
    const float* __restrict__ bv,
    unsigned short* __restrict__ Qs, unsigned short* __restrict__ Kb,
    unsigned short* __restrict__ Vb) {
    __shared__ alignas(16) char lds[65536];
    const int nt = blockIdx.y;
    const int m0 = blockIdx.x * 128;
    const int t = threadIdx.x, w = t >> 6, l = t & 63, r31 = l & 31, hi = l >> 5;
    const int wm = w >> 1, wn = w & 1;

    // staging: thread -> row t>>3 (0..31, calls +32), 16B chunk t&7
    const int rowA = t >> 3;
    const int acolS = (((t & 7) * 16) - (rowA & 7) * 16) & 127;
    const char* aSrc0 = (const char*)Xb + (long)(m0 + rowA) * 2048 + acolS;
    const char* bSrc0 = (const char*)Wt + (long)(nt * 128 + rowA) * 2048 + acolS;
    char* dst0 = lds + w * 1024;   // wave-uniform

#define PSTAGE(ST_, BUF_)                                                      \
    {                                                                          \
        const char* a_ = aSrc0 + (long)(ST_)*128;                              \
        const char* b_ = bSrc0 + (long)(ST_)*128;                              \
        char* d_ = dst0 + (BUF_)*32768;                                        \
        GLOAD16(a_, d_);                                                       \
        GLOAD16(a_ + 65536, d_ + 4096);                                        \
        GLOAD16(a_ + 131072, d_ + 8192);                                       \
        GLOAD16(a_ + 196608, d_ + 12288);                                      \
        GLOAD16(b_, d_ + 16384);                                               \
        GLOAD16(b_ + 65536, d_ + 20480);                                       \
        GLOAD16(b_ + 131072, d_ + 24576);                                      \
        GLOAD16(b_ + 196608, d_ + 28672);                                      \
    }

    // read offsets (loop-invariant): rot = (r31&7)*16 (rows mod 8)
    int aro[2][4], bro[2][4];
#pragma unroll
    for (int mi = 0; mi < 2; mi++)
#pragma unroll
        for (int ks = 0; ks < 4; ks++) {
            int rot = (ks * 32 + hi * 16 + (r31 & 7) * 16) & 127;
            aro[mi][ks] = (wm * 64 + mi * 32 + r31) * 128 + rot;
            bro[mi][ks] = 16384 + (wn * 64 + mi * 32 + r31) * 128 + rot;
        }

    f32x16 acc[2][2];
    const f32x16 oz = {};
    acc[0][0] = oz; acc[0][1] = oz; acc[1][0] = oz; acc[1][1] = oz;

    PSTAGE(0, 0);
    for (int st = 0; st < 16; st++) {
        asm volatile("s_waitcnt vmcnt(0)" ::: "memory");
        __builtin_amdgcn_sched_barrier(0);
        __builtin_amdgcn_s_barrier();
        __builtin_amdgcn_sched_barrier(0);
        if (st + 1 < 16) PSTAGE(st + 1, (st + 1) & 1);
        const char* bp = lds + (st & 1) * 32768;
        __builtin_amdgcn_s_setprio(1);
#pragma unroll
        for (int ks = 0; ks < 4; ks++) {
            bf16x8 a0 = *(const bf16x8*)(bp + aro[0][ks]);
            bf16x8 a1 = *(const bf16x8*)(bp + aro[1][ks]);
            bf16x8 b0 = *(const bf16x8*)(bp + bro[0][ks]);
            bf16x8 b1 = *(const bf16x8*)(bp + bro[1][ks]);
            acc[0][0] = MFMA32(a0, b0, acc[0][0]);
            acc[0][1] = MFMA32(a0, b1, acc[0][1]);
            acc[1][0] = MFMA32(a1, b0, acc[1][0]);
            acc[1][1] = MFMA32(a1, b1, acc[1][1]);
        }
        __builtin_amdgcn_s_setprio(0);
    }
#undef PSTAGE

    // Q scale folds 1/sqrt(128) AND log2(e) so attn softmax is pure exp2.
    const float QSCALE = 0.08838834764831845f * 1.4426950408889634f;
    const float* bias; float scale; unsigned short* outp; int ostride, ocol0, boff;
    if (nt < 2)      { bias = bq; boff = nt * 128;       scale = QSCALE; outp = Qs; ostride = 256; ocol0 = nt * 128; }
    else if (nt < 4) { bias = bk; boff = (nt - 2) * 128; scale = 1.0f;   outp = Kb; ostride = 256; ocol0 = (nt - 2) * 128; }
    else             { bias = bv; boff = 0;              scale = 1.0f;   outp = Vb; ostride = 128; ocol0 = 0; }
#pragma unroll
    for (int ni = 0; ni < 2; ni++) {
        int ncol = wn * 64 + ni * 32 + r31;
        float bb = bias[boff + ncol];
#pragma unroll
        for (int mi = 0; mi < 2; mi++) {
#pragma unroll
            for (int reg = 0; reg < 16; reg++) {
                int mrow = wm * 64 + mi * 32 + (reg & 3) + 8 * (reg >> 2) + 4 * hi;
                long row = m0 + mrow;
                outp[row * ostride + ocol0 + ncol] =
                    f2bf((acc[mi][ni][reg] + bb) * scale);
            }
        }
    }
}

// ---------------- legacy proj (fp32 X) — fallback when Xb has no room -----
__global__ __launch_bounds__(256) void proj_kernel(
    const float* __restrict__ X, const unsigned short* __restrict__ Wt,
    const float* __restrict__ bq, const float* __restrict__ bk,
    const float* __restrict__ bv,
    unsigned short* __restrict__ Qs, unsigned short* __restrict__ Kb,
    unsigned short* __restrict__ Vb) {
    __shared__ alignas(16) char lds[16384];
    const int nt = blockIdx.y;
    const int m0 = blockIdx.x * 128;
    const int t = threadIdx.x, w = t >> 6, l = t & 63, c = l & 15, g = l >> 4;
    const int wm = w >> 1, wn = w & 1;
    const unsigned short* Wrow = Wt + (long)(nt * 128) * 1024;

    f32x4 acc[4][4];
    const f32x4 fz = {0.f, 0.f, 0.f, 0.f};
#pragma unroll
    for (int i = 0; i < 4; i++)
#pragma unroll
        for (int j = 0; j < 4; j++) acc[i][j] = fz;

    const int srow = t >> 1, sh = t & 1;
    const int sswz = (srow & 7) << 4;
    for (int k0 = 0; k0 < 1024; k0 += 32) {
        const float* xs = X + (long)(m0 + srow) * 1024 + k0 + sh * 16;
        float4 f0 = *(const float4*)(xs + 0);
        float4 f1 = *(const float4*)(xs + 4);
        float4 f2 = *(const float4*)(xs + 8);
        float4 f3 = *(const float4*)(xs + 12);
        const unsigned short* wsc = Wrow + (long)srow * 1024 + k0 + sh * 16;
        uint4 w0 = *(const uint4*)(wsc + 0);
        uint4 w1 = *(const uint4*)(wsc + 8);
        uint4 xa, xb;
        xa.x = pk2bf(f0.x, f0.y); xa.y = pk2bf(f0.z, f0.w);
        xa.z = pk2bf(f1.x, f1.y); xa.w = pk2bf(f1.z, f1.w);
        xb.x = pk2bf(f2.x, f2.y); xb.y = pk2bf(f2.z, f2.w);
        xb.z = pk2bf(f3.x, f3.y); xb.w = pk2bf(f3.z, f3.w);
        int base = srow * 64 + sh * 32;
        *(uint4*)(lds + ((base + 0) ^ sswz)) = xa;
        *(uint4*)(lds + ((base + 16) ^ sswz)) = xb;
        *(uint4*)(lds + 8192 + ((base + 0) ^ sswz)) = w0;
        *(uint4*)(lds + 8192 + ((base + 16) ^ sswz)) = w1;
        __syncthreads();

        bf16x8 af[4];
#pragma unroll
        for (int am = 0; am < 4; am++) {
            int r_ = wm * 64 + am * 16 + c;
            af[am] = *(const bf16x8*)(lds + ((r_ * 64 + g * 16) ^ ((c & 7) << 4)));
        }
#pragma unroll
        for (int bn = 0; bn < 4; bn++) {
            int r_ = wn * 64 + bn * 16 + c;
            bf16x8 bfr = *(const bf16x8*)(lds + 8192 + ((r_ * 64 + g * 16) ^ ((c & 7) << 4)));
#pragma unroll
            for (int am = 0; am < 4; am++) acc[am][bn] = MFMA16(af[am], bfr, acc[am][bn]);
        }
        __syncthreads();
    }

    const float QSCALE = 0.08838834764831845f * 1.4426950408889634f;
    const float* bias; float scale; unsigned short* outp; int ostride, ocol0, boff;
    if (nt < 2)      { bias = bq; boff = nt * 128;       scale = QSCALE; outp = Qs; ostride = 256; ocol0 = nt * 128; }
    else if (nt < 4) { bias = bk; boff = (nt - 2) * 128; scale = 1.0f;   outp = Kb; ostride = 256; ocol0 = (nt - 2) * 128; }
    else             { bias = bv; boff = 0;              scale = 1.0f;   outp = Vb; ostride = 128; ocol0 = 0; }
#pragma unroll
    for (int bn = 0; bn < 4; bn++) {
        int ncol = wn * 64 + bn * 16 + c;
        float bb = bias[boff + ncol];
#pragma unroll
        for (int am = 0; am < 4; am++) {
#pragma unroll
            for (int r = 0; r < 4; r++) {
                long row = m0 + wm * 64 + am * 16 + 4 * g + r;
                outp[row * ostride + ocol0 + ncol] = f2bf((acc[am][bn][r] + bb) * scale);
            }
        }
    }
}

// ---------------- V transpose v2 (LDS-tiled): Vt[b][128][4096] ------------
// 64x64 tiles; coalesced reads AND writes; lds padded [64][72].
__global__ __launch_bounds__(256) void vtrans_kernel(
    const unsigned short* __restrict__ Vb, unsigned short* __restrict__ Vt) {
    __shared__ unsigned short lds[64][72];
    const int bid = blockIdx.x;            // 4 b x 64 sb x 2 db = 512
    const int db = bid & 1, sb = (bid >> 1) & 63, b = bid >> 7;
    const int s0 = sb * 64, d0 = db * 64;
    const int t = threadIdx.x;
    const int r = t >> 2, c4 = t & 3;
    const unsigned short* src = Vb + ((long)(b * 4096 + s0 + r)) * 128 + d0;
    uint4 u0 = *(const uint4*)(src + c4 * 8);
    uint4 u1 = *(const uint4*)(src + (c4 + 4) * 8);
    *(uint4*)(&lds[r][c4 * 8]) = u0;
    *(uint4*)(&lds[r][(c4 + 4) * 8]) = u1;
    __syncthreads();
    const int dd = t >> 2;
    unsigned short* dst = Vt + ((long)(b * 128 + d0 + dd)) * 4096 + s0;
#pragma unroll
    for (int cc2 = 0; cc2 < 2; cc2++) {
        int cc = c4 + cc2 * 4;
        unsigned short tmp[8];
#pragma unroll
        for (int j = 0; j < 8; j++) tmp[j] = lds[cc * 8 + j][dd];
        *(uint4*)(dst + cc * 8) = *(const uint4*)tmp;
    }
}

// ---------------- flash diff-attention (R8-verified) ----------------------
// 512 threads = 8 waves = 4 q-sub x 2 branches, 128 q/block.
// LDS: 4 buffers x 24KB {K1[32][256] rot | K2 | V[128][64] rot}.
// Pipeline: 3 tiles in flight; per iter ONE vmcnt(6) + ONE raw s_barrier.
__global__ __launch_bounds__(512) void attn3_kernel(
    const unsigned short* __restrict__ Qs, const unsigned short* __restrict__ Kb,
    const unsigned short* __restrict__ Vt,
    float* __restrict__ Po, float* __restrict__ Ps, int nsplit, int ks) {
    __shared__ alignas(16) char lds[98304];
    const int t = threadIdx.x;
    const int w = t >> 6, l = t & 63, r31 = l & 31, hi = l >> 5;
    const int wq = w >> 1, br = w & 1;

    const int total = gridDim.x;
    const int lin = (blockIdx.x & 7) * (total >> 3) + (blockIdx.x >> 3);
    const int grp = lin >> 5, qb = lin & 31;
    const int b = grp / nsplit, split = grp % nsplit;

    const long qrow = (long)b * 4096 + qb * 128 + wq * 32 + r31;
    bf16x8 qf[8];
    const unsigned short* Qp = Qs + qrow * 256 + br * 128 + hi * 8;
#pragma unroll
    for (int ds = 0; ds < 8; ds++) qf[ds] = *(const bf16x8*)(Qp + ds * 16);

    f32x16 o[4];
    const f32x16 oz = {};
#pragma unroll
    for (int dt = 0; dt < 4; dt++) o[dt] = oz;
    float m = -1e30f, s = 0.f;

    // --- staging geometry: wave-linear LDS dest, rotated global source ---
    const int krow = w * 4 + (l >> 4);            // K row 0..31
    const int kc = (l & 15) * 16;                 // K LDS col byte
    const int ksrc_rot = (kc - krow * 16) & 255;  // source col within 512B row
    const int vd = w * 16 + (l >> 2);             // V row (d) 0..127
    const int vc = (l & 3) * 16;
    const long kbb = (long)b * 4096;
    const char* KbB = (const char*)Kb;
    const char* VtB = (const char*)Vt + ((long)b * 128 + vd) * 8192 +
                      ((vc - ((vd >> 1) & 3) * 16) & 63);
    char* dst0 = lds + w * 1024;                  // wave-uniform

    const int kb0 = split * ks, kend = kb0 + ks;
#define STAGE(KB_, BUF_)                                                       \
    {                                                                          \
        const char* s1_ = KbB + (kbb + (KB_) + krow) * 512 + ksrc_rot;         \
        char* d_ = dst0 + (BUF_)*24576;                                        \
        GLOAD16(s1_, d_);                                                      \
        GLOAD16(s1_ + 256, d_ + 8192);                                         \
        GLOAD16(VtB + (long)(KB_)*2, d_ + 16384);                              \
    }

    int kro[8];
#pragma unroll
    for (int ds = 0; ds < 8; ds++)
        kro[ds] = br * 8192 + r31 * 256 + ((ds * 32 + hi * 16 + r31 * 16) & 255);
    int vro0[4], vro1[4];
#pragma unroll
    for (int dt = 0; dt < 4; dt++) {
        int vr = dt * 32 + r31, rot = ((vr >> 1) & 3) * 16;
        vro0[dt] = 16384 + vr * 64 + ((hi * 16 + rot) & 63);
        vro1[dt] = 16384 + vr * 64 + ((32 + hi * 16 + rot) & 63);
    }

    STAGE(kb0, 0);
    STAGE(kb0 + 32, 1);
    STAGE(kb0 + 64, 2);
    int cur = 0;

    for (int kb = kb0; kb < kend; kb += 32) {
        asm volatile("s_waitcnt vmcnt(6)" ::: "memory");
        __builtin_amdgcn_sched_barrier(0);
        __builtin_amdgcn_s_barrier();
        asm volatile("" ::: "memory");
        __builtin_amdgcn_sched_barrier(0);
        {
            int kn = kb + 96;
            if (kn >= kend) kn = kb0;
            STAGE(kn, (cur + 3) & 3);
        }
        const char* bufp = lds + cur * 24576;

        // ---- QK^T: P^T[key][q], two independent 4-deep chains ----
        f32x16 pa = oz, pb_ = oz;
        __builtin_amdgcn_s_setprio(1);
#pragma unroll
        for (int ds = 0; ds < 4; ds++) {
            bf16x8 kfa = *(const bf16x8*)(bufp + kro[ds]);
            bf16x8 kfb = *(const bf16x8*)(bufp + kro[ds + 4]);
            pa = MFMA32(kfa, qf[ds], pa);
            pb_ = MFMA32(kfb, qf[ds + 4], pb_);
        }
        __builtin_amdgcn_s_setprio(0);
        f32x16 p;
#pragma unroll
        for (int i = 0; i < 16; i++) p[i] = pa[i] + pb_[i];

        // ---- in-register softmax (exp2 domain; defer-max THR=8) ----
        float x0 = fmaxf(fmaxf(p[0], p[1]), fmaxf(p[2], p[3]));
        float x1 = fmaxf(fmaxf(p[4], p[5]), fmaxf(p[6], p[7]));
        float x2 = fmaxf(fmaxf(p[8], p[9]), fmaxf(p[10], p[11]));
        float x3 = fmaxf(fmaxf(p[12], p[13]), fmaxf(p[14], p[15]));
        float lmx = fmaxf(fmaxf(x0, x1), fmaxf(x2, x3));
        lmx = fmaxf(lmx, __shfl_xor(lmx, 32));
        if (__any(lmx > m + 8.f)) {
            float mn = fmaxf(m, lmx);
            float al = fexp2(m - mn);
            s *= al; m = mn;
#pragma unroll
            for (int dt = 0; dt < 4; dt++) o[dt] *= al;
        }
        float pe[16];
#pragma unroll
        for (int i = 0; i < 16; i++) pe[i] = fexp2(p[i] - m);
        float s0 = (pe[0] + pe[1]) + (pe[2] + pe[3]);
        float s1 = (pe[4] + pe[5]) + (pe[6] + pe[7]);
        float s2 = (pe[8] + pe[9]) + (pe[10] + pe[11]);
        float s3 = (pe[12] + pe[13]) + (pe[14] + pe[15]);
        float ps_ = (s0 + s1) + (s2 + s3);
        ps_ += __shfl_xor(ps_, 32);
        s += ps_;

        // ---- P -> PV B-fragments (cvt_pk + permlane32_swap) ----
        unsigned cA = pk2bf(pe[0], pe[1]), cB = pk2bf(pe[2], pe[3]);
        unsigned cC = pk2bf(pe[4], pe[5]), cD = pk2bf(pe[6], pe[7]);
        asm volatile("v_permlane32_swap_b32 %0, %1" : "+v"(cA), "+v"(cC));
        asm volatile("v_permlane32_swap_b32 %0, %1" : "+v"(cB), "+v"(cD));
        unsigned dA = pk2bf(pe[8], pe[9]), dB = pk2bf(pe[10], pe[11]);
        unsigned dC = pk2bf(pe[12], pe[13]), dD = pk2bf(pe[14], pe[15]);
        asm volatile("v_permlane32_swap_b32 %0, %1" : "+v"(dA), "+v"(dC));
        asm volatile("v_permlane32_swap_b32 %0, %1" : "+v"(dB), "+v"(dD));
        union { uint4 u; bf16x8 v; } pb0, pb1;
        pb0.u = uint4{cA, cB, cC, cD};   // keys 0-15
        pb1.u = uint4{dA, dB, dC, dD};   // keys 16-31

        // ---- PV: O^T[d][q] += V^T-frag x PB ----
        __builtin_amdgcn_s_setprio(1);
#pragma unroll
        for (int dt = 0; dt < 4; dt++) {
            bf16x8 vf0 = *(const bf16x8*)(bufp + vro0[dt]);
            bf16x8 vf1 = *(const bf16x8*)(bufp + vro1[dt]);
            o[dt] = MFMA32(vf0, pb0.v, o[dt]);
            o[dt] = MFMA32(vf1, pb1.v, o[dt]);
        }
        __builtin_amdgcn_s_setprio(0);
        cur = (cur + 1) & 3;
    }

    float* po = Po + ((qrow * nsplit + split) * 2 + br) * 128;
#pragma unroll
    for (int dt = 0; dt < 4; dt++) {
#pragma unroll
        for (int rg = 0; rg < 4; rg++) {
            float4 v;   // d = dt*32 + rg*8 + hi*4 + j
            v.x = o[dt][rg * 4 + 0];
            v.y = o[dt][rg * 4 + 1];
            v.z = o[dt][rg * 4 + 2];
            v.w = o[dt][rg * 4 + 3];
            *(float4*)(po + dt * 32 + rg * 8 + hi * 4) = v;
        }
    }
    if (hi == 0)
        *(float2*)(Ps + (qrow * nsplit + split) * 4 + br * 2) = float2{m, s};
#undef STAGE
}

// ---------------- split combine ----------------
__global__ __launch_bounds__(256) void combine_kernel(
    const float* __restrict__ Po, const float* __restrict__ Ps,
    const float* __restrict__ lam_p, float* __restrict__ out, int nsplit) {
    int tid = blockIdx.x * 256 + threadIdx.x;   // 16384 q * 32 threads
    int q = tid >> 5, dq = (tid & 31) * 4;
    float M1 = -1e30f, M2 = -1e30f;
    for (int s = 0; s < nsplit; s++) {
        float4 st = *(const float4*)(Ps + (long)(q * nsplit + s) * 4);
        M1 = fmaxf(M1, st.x); M2 = fmaxf(M2, st.z);
    }
    float S1 = 0.f, S2 = 0.f;
    float a0 = 0.f, a1 = 0.f, a2 = 0.f, a3 = 0.f;
    float b0 = 0.f, b1 = 0.f, b2 = 0.f, b3 = 0.f;
    for (int s = 0; s < nsplit; s++) {
        float4 st = *(const float4*)(Ps + (long)(q * nsplit + s) * 4);
        float w1 = fexp2(st.x - M1), w2 = fexp2(st.z - M2);
        S1 += st.y * w1; S2 += st.w * w2;
        const float* p1 = Po + (((long)q * nsplit + s) * 2 + 0) * 128 + dq;
        const float* p2 = Po + (((long)q * nsplit + s) * 2 + 1) * 128 + dq;
        float4 v1 = *(const float4*)p1;
        float4 v2 = *(const float4*)p2;
        a0 += v1.x * w1; a1 += v1.y * w1; a2 += v1.z * w1; a3 += v1.w * w1;
        b0 += v2.x * w2; b1 += v2.y * w2; b2 += v2.z * w2; b3 += v2.w * w2;
    }
    float lam = *lam_p;
    float i1 = 1.f / S1, i2 = lam / S2;
    float4 v;
    v.x = a0 * i1 - b0 * i2;
    v.y = a1 * i1 - b1 * i2;
    v.z = a2 * i1 - b2 * i2;
    v.w = a3 * i1 - b3 * i2;
    *(float4*)(out + (long)q * 128 + dq) = v;
}

extern "C" void kernel_launch(void* const* d_in, const int* in_sizes, int n_in,
                              void* d_out, int out_size, void* d_ws, size_t ws_size,
                              hipStream_t stream) {
    const float* X   = (const float*)d_in[0];
    const float* lam = (const float*)d_in[1];
    const float* Wq  = (const float*)d_in[2];
    const float* bq  = (const float*)d_in[3];
    const float* Wk  = (const float*)d_in[4];
    const float* bk  = (const float*)d_in[5];
    const float* Wv  = (const float*)d_in[6];
    const float* bv  = (const float*)d_in[7];
    char* ws = (char*)d_ws;
    // ws: Qs 8M | Kb 8M | Vb 4M | Vt 4M | Wt 1.25M | @26M: Po, Ps
    // Xb (32 MiB) aliases Po: written by xcvt, read by proj2, dead before attn.
    unsigned short* Qs = (unsigned short*)(ws);
    unsigned short* Kb = (unsigned short*)(ws + (8u << 20));
    unsigned short* Vb = (unsigned short*)(ws + (16u << 20));
    unsigned short* Vt = (unsigned short*)(ws + (20u << 20));
    unsigned short* Wt = (unsigned short*)(ws + (24u << 20));
    const size_t base = (size_t)26 << 20;
    const size_t NQ = 16384;
    int nsplit = 1;
    if (ws_size >= base + NQ * 4 * 2 * 128 * 4 + NQ * 4 * 4 * 4)      nsplit = 4;
    else if (ws_size >= base + NQ * 2 * 2 * 128 * 4 + NQ * 2 * 4 * 4) nsplit = 2;
    float* Po = (float*)(ws + base);
    float* Ps = (float*)(ws + base + NQ * (size_t)nsplit * 2 * 128 * 4);
    unsigned short* Xb = (unsigned short*)(ws + base);   // aliases Po

    wtrans_kernel<<<2560, 256, 0, stream>>>(Wq, Wk, Wv, Wt);
    if (nsplit >= 2) {   // Po region (>= 32 MiB) has room for Xb
        xcvt_kernel<<<8192, 256, 0, stream>>>(X, Xb);
        proj2_kernel<<<dim3(128, 5), 256, 0, stream>>>(Xb, Wt, bq, bk, bv,
                                                       Qs, Kb, Vb);
    } else {
        proj_kernel<<<dim3(128, 5), 256, 0, stream>>>(X, Wt, bq, bk, bv,
                                                      Qs, Kb, Vb);
    }
    vtrans_kernel<<<512, 256, 0, stream>>>(Vb, Vt);
    attn3_kernel<<<128 * nsplit, 512, 0, stream>>>(Qs, Kb, Vt, Po, Ps,
                                                   nsplit, 4096 / nsplit);
    combine_kernel<<<2048, 256, 0, stream>>>(Po, Ps, lam, (float*)d_out, nsplit);
}

// Round 14
// 172.148 us; speedup vs baseline: 1.0031x; 1.0031x over previous
//
#include <hip/hip_runtime.h>
#include <hip/hip_bf16.h>

// DiffAttn: B=4, S=4096, EMB=1024, D=128
//   Q = X@Wq+bq (256 cols = Q1|Q2), K likewise, V = X@Wv+bv (128)
//   out = softmax(Q1K1^T/sqrt(D))@V - lam*softmax(Q2K2^T/sqrt(D))@V
// attn v9.1: 3-stream per-wave pipeline (QK(i+1) + PV(i-1) issued before
// softmax(i) VALU). vs R13: cross-half reductions reverted to the VERIFIED
// __shfl_xor(32) (R13's xhalf helpers could register-coalesce both asm
// operands into one VGPR -> degenerate permlane swap -> wrong max).
// 5 LDS buffers, vmcnt(3) fences, 2x-unrolled loop with named A/B states.

typedef __attribute__((ext_vector_type(8))) short bf16x8;    // 8 bf16
typedef __attribute__((ext_vector_type(4))) float f32x4;
typedef __attribute__((ext_vector_type(16))) float f32x16;   // 32x32 C/D

#define MFMA16(a, b, c) __builtin_amdgcn_mfma_f32_16x16x32_bf16((a), (b), (c), 0, 0, 0)
#define MFMA32(a, b, c) __builtin_amdgcn_mfma_f32_32x32x16_bf16((a), (b), (c), 0, 0, 0)

typedef const __attribute__((address_space(1))) void gas_void;
typedef __attribute__((address_space(3))) void las_void;
#define GLOAD16(G, L) __builtin_amdgcn_global_load_lds((gas_void*)(G), (las_void*)(L), 16, 0, 0)

__device__ __forceinline__ unsigned short f2bf(float x) {
    union { float f; unsigned u; } v; v.f = x;   // RNE float->bf16
    return (unsigned short)((v.u + 0x7FFFu + ((v.u >> 16) & 1u)) >> 16);
}
__device__ __forceinline__ unsigned pk2bf(float a, float b) {   // v_cvt_pk_bf16_f32
    __hip_bfloat162 h = __float22bfloat162_rn(float2{a, b});
    union { __hip_bfloat162 h2; unsigned u; } cv; cv.h2 = h;
    return cv.u;
}
__device__ __forceinline__ float fexp2(float x) {   // raw v_exp_f32: D = 2^S0
    float r; asm("v_exp_f32 %0, %1" : "=v"(r) : "v"(x)); return r;
}

// ---------------- W transpose + bf16 convert: Wt[640][1024] ----------------
__global__ __launch_bounds__(256) void wtrans_kernel(
    const float* __restrict__ Wq, const float* __restrict__ Wk,
    const float* __restrict__ Wv, unsigned short* __restrict__ Wt) {
    int tid = blockIdx.x * 256 + threadIdx.x;   // 640*1024 total
    int k = tid & 1023, n = tid >> 10;
    float v;
    if (n < 256)      v = Wq[k * 256 + n];
    else if (n < 512) v = Wk[k * 256 + (n - 256)];
    else              v = Wv[k * 128 + (n - 512)];
    Wt[tid] = f2bf(v);
}

// ---------------- QKV projection GEMM (fp32 X, verified) ----------------
__global__ __launch_bounds__(256) void proj_kernel(
    const float* __restrict__ X, const unsigned short* __restrict__ Wt,
    const float* __restrict__ bq, const float* __restrict__ bk,
    const float* __restrict__ bv,
    unsigned short* __restrict__ Qs, unsigned short* __restrict__ Kb,
    unsigned short* __restrict__ Vb) {
    __shared__ alignas(16) char lds[16384];
    const int nt = blockIdx.y;
    const int m0 = blockIdx.x * 128;
    const int t = threadIdx.x, w = t >> 6, l = t & 63, c = l & 15, g = l >> 4;
    const int wm = w >> 1, wn = w & 1;
    const unsigned short* Wrow = Wt + (long)(nt * 128) * 1024;

    f32x4 acc[4][4];
    const f32x4 fz = {0.f, 0.f, 0.f, 0.f};
#pragma unroll
    for (int i = 0; i < 4; i++)
#pragma unroll
        for (int j = 0; j < 4; j++) acc[i][j] = fz;

    const int srow = t >> 1, sh = t & 1;
    const int sswz = (srow & 7) << 4;
    for (int k0 = 0; k0 < 1024; k0 += 32) {
        const float* xs = X + (long)(m0 + srow) * 1024 + k0 + sh * 16;
        float4 f0 = *(const float4*)(xs + 0);
        float4 f1 = *(const float4*)(xs + 4);
        float4 f2 = *(const float4*)(xs + 8);
        float4 f3 = *(const float4*)(xs + 12);
        const unsigned short* wsc = Wrow + (long)srow * 1024 + k0 + sh * 16;
        uint4 w0 = *(const uint4*)(wsc + 0);
        uint4 w1 = *(const uint4*)(wsc + 8);
        uint4 xa, xb;
        xa.x = pk2bf(f0.x, f0.y); xa.y = pk2bf(f0.z, f0.w);
        xa.z = pk2bf(f1.x, f1.y); xa.w = pk2bf(f1.z, f1.w);
        xb.x = pk2bf(f2.x, f2.y); xb.y = pk2bf(f2.z, f2.w);
        xb.z = pk2bf(f3.x, f3.y); xb.w = pk2bf(f3.z, f3.w);
        int base = srow * 64 + sh * 32;
        *(uint4*)(lds + ((base + 0) ^ sswz)) = xa;
        *(uint4*)(lds + ((base + 16) ^ sswz)) = xb;
        *(uint4*)(lds + 8192 + ((base + 0) ^ sswz)) = w0;
        *(uint4*)(lds + 8192 + ((base + 16) ^ sswz)) = w1;
        __syncthreads();

        bf16x8 af[4];
#pragma unroll
        for (int am = 0; am < 4; am++) {
            int r_ = wm * 64 + am * 16 + c;
            af[am] = *(const bf16x8*)(lds + ((r_ * 64 + g * 16) ^ ((c & 7) << 4)));
        }
#pragma unroll
        for (int bn = 0; bn < 4; bn++) {
            int r_ = wn * 64 + bn * 16 + c;
            bf16x8 bfr = *(const bf16x8*)(lds + 8192 + ((r_ * 64 + g * 16) ^ ((c & 7) << 4)));
#pragma unroll
            for (int am = 0; am < 4; am++) acc[am][bn] = MFMA16(af[am], bfr, acc[am][bn]);
        }
        __syncthreads();
    }

    // Q scale folds 1/sqrt(128) AND log2(e) so attn softmax is pure exp2.
    const float QSCALE = 0.08838834764831845f * 1.4426950408889634f;
    const float* bias; float scale; unsigned short* outp; int ostride, ocol0, boff;
    if (nt < 2)      { bias = bq; boff = nt * 128;       scale = QSCALE; outp = Qs; ostride = 256; ocol0 = nt * 128; }
    else if (nt < 4) { bias = bk; boff = (nt - 2) * 128; scale = 1.0f;   outp = Kb; ostride = 256; ocol0 = (nt - 2) * 128; }
    else             { bias = bv; boff = 0;              scale = 1.0f;   outp = Vb; ostride = 128; ocol0 = 0; }
#pragma unroll
    for (int bn = 0; bn < 4; bn++) {
        int ncol = wn * 64 + bn * 16 + c;
        float bb = bias[boff + ncol];
#pragma unroll
        for (int am = 0; am < 4; am++) {
#pragma unroll
            for (int r = 0; r < 4; r++) {
                long row = m0 + wm * 64 + am * 16 + 4 * g + r;
                outp[row * ostride + ocol0 + ncol] = f2bf((acc[am][bn][r] + bb) * scale);
            }
        }
    }
}

// ---------------- V transpose (LDS-tiled): Vt[b][128][4096] ------------
__global__ __launch_bounds__(256) void vtrans_kernel(
    const unsigned short* __restrict__ Vb, unsigned short* __restrict__ Vt) {
    __shared__ unsigned short lds[64][72];
    const int bid = blockIdx.x;            // 4 b x 64 sb x 2 db = 512
    const int db = bid & 1, sb = (bid >> 1) & 63, b = bid >> 7;
    const int s0 = sb * 64, d0 = db * 64;
    const int t = threadIdx.x;
    const int r = t >> 2, c4 = t & 3;
    const unsigned short* src = Vb + ((long)(b * 4096 + s0 + r)) * 128 + d0;
    uint4 u0 = *(const uint4*)(src + c4 * 8);
    uint4 u1 = *(const uint4*)(src + (c4 + 4) * 8);
    *(uint4*)(&lds[r][c4 * 8]) = u0;
    *(uint4*)(&lds[r][(c4 + 4) * 8]) = u1;
    __syncthreads();
    const int dd = t >> 2;
    unsigned short* dst = Vt + ((long)(b * 128 + d0 + dd)) * 4096 + s0;
#pragma unroll
    for (int cc2 = 0; cc2 < 2; cc2++) {
        int cc = c4 + cc2 * 4;
        unsigned short tmp[8];
#pragma unroll
        for (int j = 0; j < 8; j++) tmp[j] = lds[cc * 8 + j][dd];
        *(uint4*)(dst + cc * 8) = *(const uint4*)tmp;
    }
}

// ---------------- flash diff-attention v9.1 (3-stream pipeline) -----------
// 512 threads = 8 waves = 4 q-sub x 2 branches, 128 q/block.
// LDS: 5 buffers x 24KB {K1[32][256B] rot | K2 | V[128][64B] rot}.
__global__ __launch_bounds__(512, 2) void attn4_kernel(
    const unsigned short* __restrict__ Qs, const unsigned short* __restrict__ Kb,
    const unsigned short* __restrict__ Vt,
    float* __restrict__ Po, float* __restrict__ Ps, int nsplit, int ks) {
    __shared__ alignas(16) char lds[122880];   // 5 x 24576
    const int t = threadIdx.x;
    const int w = t >> 6, l = t & 63, r31 = l & 31, hi = l >> 5;
    const int wq = w >> 1, br = w & 1;

    const int total = gridDim.x;
    const int lin = (blockIdx.x & 7) * (total >> 3) + (blockIdx.x >> 3);
    const int grp = lin >> 5, qb = lin & 31;
    const int b = grp / nsplit, split = grp % nsplit;

    const long qrow = (long)b * 4096 + qb * 128 + wq * 32 + r31;
    bf16x8 qf[8];
    const unsigned short* Qp = Qs + qrow * 256 + br * 128 + hi * 8;
#pragma unroll
    for (int ds = 0; ds < 8; ds++) qf[ds] = *(const bf16x8*)(Qp + ds * 16);

    f32x16 o[4];
    const f32x16 oz = {};
#pragma unroll
    for (int dt = 0; dt < 4; dt++) o[dt] = oz;
    float m = -1e30f, s = 0.f;

    // --- staging geometry: wave-linear LDS dest, rotated global source ---
    const int krow = w * 4 + (l >> 4);            // K row 0..31
    const int kc = (l & 15) * 16;                 // K LDS col byte
    const int ksrc_rot = (kc - krow * 16) & 255;  // source col within 512B row
    const int vd = w * 16 + (l >> 2);             // V row (d) 0..127
    const int vc = (l & 3) * 16;
    const long kbb = (long)b * 4096;
    const char* KbB = (const char*)Kb;
    const char* VtB = (const char*)Vt + ((long)b * 128 + vd) * 8192 +
                      ((vc - ((vd >> 1) & 3) * 16) & 63);
    char* dst0 = lds + w * 1024;                  // wave-uniform

    const int kb0 = split * ks;
    const int nt = ks >> 5;                       // 32-key tiles (even)
#define STAGE(KB_, BUF_)                                                       \
    {                                                                          \
        const char* s1_ = KbB + (kbb + (KB_) + krow) * 512 + ksrc_rot;         \
        char* d_ = dst0 + (BUF_)*24576;                                        \
        GLOAD16(s1_, d_);                                                      \
        GLOAD16(s1_ + 256, d_ + 8192);                                         \
        GLOAD16(VtB + (long)(KB_)*2, d_ + 16384);                              \
    }

    int kro[8];
#pragma unroll
    for (int ds = 0; ds < 8; ds++)
        kro[ds] = br * 8192 + r31 * 256 + ((ds * 32 + hi * 16 + r31 * 16) & 255);
    int vro0[4], vro1[4];
#pragma unroll
    for (int dt = 0; dt < 4; dt++) {
        int vr = dt * 32 + r31, rot = ((vr >> 1) & 3) * 16;
        vro0[dt] = 16384 + vr * 64 + ((hi * 16 + rot) & 63);
        vro1[dt] = 16384 + vr * 64 + ((32 + hi * 16 + rot) & 63);
    }

    // QK of the tile in buffer BI_ -> accumulate into QA_/QB_ (pre-zeroed)
#define QKTILE(QA_, QB_, BI_)                                                  \
    {                                                                          \
        const char* kp_ = lds + (BI_)*24576;                                   \
        _Pragma("unroll") for (int d_ = 0; d_ < 4; d_++) {                     \
            bf16x8 ka_ = *(const bf16x8*)(kp_ + kro[d_]);                      \
            bf16x8 kb2_ = *(const bf16x8*)(kp_ + kro[d_ + 4]);                 \
            QA_ = MFMA32(ka_, qf[d_], QA_);                                    \
            QB_ = MFMA32(kb2_, qf[d_ + 4], QB_);                               \
        }                                                                      \
    }

    // PV using P-fragments PK0_/PK1_ and the V in buffer BI_
#define PVTILE(PK0_, PK1_, BI_)                                                \
    {                                                                          \
        const char* vb_ = lds + (BI_)*24576;                                   \
        union { uint4 u; bf16x8 v; } u0_, u1_;                                 \
        u0_.u = PK0_; u1_.u = PK1_;                                            \
        _Pragma("unroll") for (int dt_ = 0; dt_ < 4; dt_++) {                  \
            bf16x8 vf0 = *(const bf16x8*)(vb_ + vro0[dt_]);                    \
            bf16x8 vf1 = *(const bf16x8*)(vb_ + vro1[dt_]);                    \
            o[dt_] = MFMA32(vf0, u0_.v, o[dt_]);                               \
            o[dt_] = MFMA32(vf1, u1_.v, o[dt_]);                               \
        }                                                                      \
    }

    // softmax: merge QC0+=QC1, reduce (verified __shfl_xor), exp, sum,
    // build P-frags into PD0/PD1
#define SOFTMAX(QC0, QC1, PD0, PD1)                                            \
    {                                                                          \
        _Pragma("unroll") for (int i_ = 0; i_ < 16; i_++) QC0[i_] += QC1[i_];  \
        float x0 = fmaxf(fmaxf(QC0[0], QC0[1]), fmaxf(QC0[2], QC0[3]));        \
        float x1 = fmaxf(fmaxf(QC0[4], QC0[5]), fmaxf(QC0[6], QC0[7]));        \
        float x2 = fmaxf(fmaxf(QC0[8], QC0[9]), fmaxf(QC0[10], QC0[11]));      \
        float x3 = fmaxf(fmaxf(QC0[12], QC0[13]), fmaxf(QC0[14], QC0[15]));    \
        float lmx = fmaxf(fmaxf(x0, x1), fmaxf(x2, x3));                       \
        lmx = fmaxf(lmx, __shfl_xor(lmx, 32));                                 \
        if (__any(lmx > m + 8.f)) {                                            \
            float mn = fmaxf(m, lmx);                                          \
            float al = fexp2(m - mn);                                          \
            s *= al; m = mn;                                                   \
            _Pragma("unroll") for (int dt_ = 0; dt_ < 4; dt_++) o[dt_] *= al;  \
        }                                                                      \
        float pe[16];                                                          \
        _Pragma("unroll") for (int i_ = 0; i_ < 16; i_++)                      \
            pe[i_] = fexp2(QC0[i_] - m);                                       \
        float s0_ = (pe[0] + pe[1]) + (pe[2] + pe[3]);                         \
        float s1_ = (pe[4] + pe[5]) + (pe[6] + pe[7]);                         \
        float s2_ = (pe[8] + pe[9]) + (pe[10] + pe[11]);                       \
        float s3_ = (pe[12] + pe[13]) + (pe[14] + pe[15]);                     \
        float ps_ = (s0_ + s1_) + (s2_ + s3_);                                 \
        ps_ += __shfl_xor(ps_, 32);                                            \
        s += ps_;                                                              \
        unsigned cA = pk2bf(pe[0], pe[1]), cB = pk2bf(pe[2], pe[3]);           \
        unsigned cC = pk2bf(pe[4], pe[5]), cD = pk2bf(pe[6], pe[7]);           \
        asm volatile("v_permlane32_swap_b32 %0, %1" : "+v"(cA), "+v"(cC));     \
        asm volatile("v_permlane32_swap_b32 %0, %1" : "+v"(cB), "+v"(cD));     \
        unsigned dA = pk2bf(pe[8], pe[9]), dB = pk2bf(pe[10], pe[11]);         \
        unsigned dC = pk2bf(pe[12], pe[13]), dD = pk2bf(pe[14], pe[15]);       \
        asm volatile("v_permlane32_swap_b32 %0, %1" : "+v"(dA), "+v"(dC));     \
        asm volatile("v_permlane32_swap_b32 %0, %1" : "+v"(dB), "+v"(dD));     \
        PD0 = uint4{cA, cB, cC, cD};                                           \
        PD1 = uint4{dA, dB, dC, dD};                                           \
    }

    // per-iter body: fence; stage(I+3); issue QK(I+1); issue PV(I-1);
    // then softmax(I) VALU (overlaps the in-flight MFMA streams).
#define BODY(QC0, QC1, QN0, QN1, PU0, PU1, PD0, PD1, I_)                       \
    {                                                                          \
        asm volatile("s_waitcnt vmcnt(3)" ::: "memory");                       \
        __builtin_amdgcn_sched_barrier(0);                                     \
        __builtin_amdgcn_s_barrier();                                          \
        __builtin_amdgcn_sched_barrier(0);                                     \
        {                                                                      \
            int i3_ = (I_) + 3;                                                \
            int kn_ = (i3_ < nt) ? kb0 + (i3_ << 5) : kb0;                     \
            STAGE(kn_, i3_ % 5);                                               \
        }                                                                      \
        QN0 = oz; QN1 = oz;                                                    \
        __builtin_amdgcn_s_setprio(1);                                         \
        if ((I_) + 1 < nt) QKTILE(QN0, QN1, ((I_) + 1) % 5)                    \
        if ((I_) > 0) PVTILE(PU0, PU1, ((I_) + 4) % 5)                         \
        __builtin_amdgcn_s_setprio(0);                                         \
        SOFTMAX(QC0, QC1, PD0, PD1)                                            \
    }

    // prologue: 3 tiles staged; QK(0) computed ahead
    STAGE(kb0, 0);
    STAGE(kb0 + 32, 1);
    STAGE(kb0 + 64, 2);
    asm volatile("s_waitcnt vmcnt(6)" ::: "memory");
    __builtin_amdgcn_sched_barrier(0);
    __builtin_amdgcn_s_barrier();
    __builtin_amdgcn_sched_barrier(0);
    f32x16 qaA = oz, qbA = oz, qaB = oz, qbB = oz;
    QKTILE(qaA, qbA, 0)
    uint4 pkA0 = {0, 0, 0, 0}, pkA1 = {0, 0, 0, 0};
    uint4 pkB0 = {0, 0, 0, 0}, pkB1 = {0, 0, 0, 0};

    for (int it = 0; it < nt; it += 2) {
        BODY(qaA, qbA, qaB, qbB, pkB0, pkB1, pkA0, pkA1, it)
        BODY(qaB, qbB, qaA, qbA, pkA0, pkA1, pkB0, pkB1, it + 1)
    }
    // epilogue PV(nt-1): last softmax (odd iter) defined pkB
    PVTILE(pkB0, pkB1, (nt + 4) % 5)
    asm volatile("s_waitcnt vmcnt(0)" ::: "memory");

    float* po = Po + ((qrow * nsplit + split) * 2 + br) * 128;
#pragma unroll
    for (int dt = 0; dt < 4; dt++) {
#pragma unroll
        for (int rg = 0; rg < 4; rg++) {
            float4 v;   // d = dt*32 + rg*8 + hi*4 + j
            v.x = o[dt][rg * 4 + 0];
            v.y = o[dt][rg * 4 + 1];
            v.z = o[dt][rg * 4 + 2];
            v.w = o[dt][rg * 4 + 3];
            *(float4*)(po + dt * 32 + rg * 8 + hi * 4) = v;
        }
    }
    if (hi == 0)
        *(float2*)(Ps + (qrow * nsplit + split) * 4 + br * 2) = float2{m, s};
#undef STAGE
#undef QKTILE
#undef PVTILE
#undef SOFTMAX
#undef BODY
}

// ---------------- split combine ----------------
__global__ __launch_bounds__(256) void combine_kernel(
    const float* __restrict__ Po, const float* __restrict__ Ps,
    const float* __restrict__ lam_p, float* __restrict__ out, int nsplit) {
    int tid = blockIdx.x * 256 + threadIdx.x;   // 16384 q * 32 threads
    int q = tid >> 5, dq = (tid & 31) * 4;
    float M1 = -1e30f, M2 = -1e30f;
    for (int s = 0; s < nsplit; s++) {
        float4 st = *(const float4*)(Ps + (long)(q * nsplit + s) * 4);
        M1 = fmaxf(M1, st.x); M2 = fmaxf(M2, st.z);
    }
    float S1 = 0.f, S2 = 0.f;
    float a0 = 0.f, a1 = 0.f, a2 = 0.f, a3 = 0.f;
    float b0 = 0.f, b1 = 0.f, b2 = 0.f, b3 = 0.f;
    for (int s = 0; s < nsplit; s++) {
        float4 st = *(const float4*)(Ps + (long)(q * nsplit + s) * 4);
        float w1 = fexp2(st.x - M1), w2 = fexp2(st.z - M2);
        S1 += st.y * w1; S2 += st.w * w2;
        const float* p1 = Po + (((long)q * nsplit + s) * 2 + 0) * 128 + dq;
        const float* p2 = Po + (((long)q * nsplit + s) * 2 + 1) * 128 + dq;
        float4 v1 = *(const float4*)p1;
        float4 v2 = *(const float4*)p2;
        a0 += v1.x * w1; a1 += v1.y * w1; a2 += v1.z * w1; a3 += v1.w * w1;
        b0 += v2.x * w2; b1 += v2.y * w2; b2 += v2.z * w2; b3 += v2.w * w2;
    }
    float lam = *lam_p;
    float i1 = 1.f / S1, i2 = lam / S2;
    float4 v;
    v.x = a0 * i1 - b0 * i2;
    v.y = a1 * i1 - b1 * i2;
    v.z = a2 * i1 - b2 * i2;
    v.w = a3 * i1 - b3 * i2;
    *(float4*)(out + (long)q * 128 + dq) = v;
}

extern "C" void kernel_launch(void* const* d_in, const int* in_sizes, int n_in,
                              void* d_out, int out_size, void* d_ws, size_t ws_size,
                              hipStream_t stream) {
    const float* X   = (const float*)d_in[0];
    const float* lam = (const float*)d_in[1];
    const float* Wq  = (const float*)d_in[2];
    const float* bq  = (const float*)d_in[3];
    const float* Wk  = (const float*)d_in[4];
    const float* bk  = (const float*)d_in[5];
    const float* Wv  = (const float*)d_in[6];
    const float* bv  = (const float*)d_in[7];
    char* ws = (char*)d_ws;
    // ws: Qs 8M | Kb 8M | Vb 4M | Vt 4M | Wt 1.25M | @26M: Po, Ps
    unsigned short* Qs = (unsigned short*)(ws);
    unsigned short* Kb = (unsigned short*)(ws + (8u << 20));
    unsigned short* Vb = (unsigned short*)(ws + (16u << 20));
    unsigned short* Vt = (unsigned short*)(ws + (20u << 20));
    unsigned short* Wt = (unsigned short*)(ws + (24u << 20));
    const size_t base = (size_t)26 << 20;
    const size_t NQ = 16384;
    int nsplit = 1;
    if (ws_size >= base + NQ * 4 * 2 * 128 * 4 + NQ * 4 * 4 * 4)      nsplit = 4;
    else if (ws_size >= base + NQ * 2 * 2 * 128 * 4 + NQ * 2 * 4 * 4) nsplit = 2;
    float* Po = (float*)(ws + base);
    float* Ps = (float*)(ws + base + NQ * (size_t)nsplit * 2 * 128 * 4);

    wtrans_kernel<<<2560, 256, 0, stream>>>(Wq, Wk, Wv, Wt);
    proj_kernel<<<dim3(128, 5), 256, 0, stream>>>(X, Wt, bq, bk, bv, Qs, Kb, Vb);
    vtrans_kernel<<<512, 256, 0, stream>>>(Vb, Vt);
    attn4_kernel<<<128 * nsplit, 512, 0, stream>>>(Qs, Kb, Vt, Po, Ps,
                                                   nsplit, 4096 / nsplit);
    combine_kernel<<<2048, 256, 0, stream>>>(Po, Ps, lam, (float*)d_out, nsplit);
}

// Round 15
// 157.349 us; speedup vs baseline: 1.0974x; 1.0941x over previous
//
#include <hip/hip_runtime.h>
#include <hip/hip_bf16.h>

// DiffAttn: B=4, S=4096, EMB=1024, D=128
//   Q = X@Wq+bq (256 cols = Q1|Q2), K likewise, V = X@Wv+bv (128)
//   out = softmax(Q1K1^T/sqrt(D))@V - lam*softmax(Q2K2^T/sqrt(D))@V
// attn v8.1: R11's KVBLK=64 kernel with the reductions FIXED (R11's only
// bug was xhalf_* register-coalescing: both "+v" operands of
// v_permlane32_swap got the same VGPR -> degenerate swap; replaced with
// the verified __shfl_xor(32)). 256 thr = 4 waves x 32q, one branch per
// block; 2 x 32KB LDS double-buffer; global_load_lds pre-rotated staging.

typedef __attribute__((ext_vector_type(8))) short bf16x8;    // 8 bf16
typedef __attribute__((ext_vector_type(4))) float f32x4;
typedef __attribute__((ext_vector_type(16))) float f32x16;   // 32x32 C/D

#define MFMA16(a, b, c) __builtin_amdgcn_mfma_f32_16x16x32_bf16((a), (b), (c), 0, 0, 0)
#define MFMA32(a, b, c) __builtin_amdgcn_mfma_f32_32x32x16_bf16((a), (b), (c), 0, 0, 0)

typedef const __attribute__((address_space(1))) void gas_void;
typedef __attribute__((address_space(3))) void las_void;
#define GLOAD16(G, L) __builtin_amdgcn_global_load_lds((gas_void*)(G), (las_void*)(L), 16, 0, 0)

__device__ __forceinline__ unsigned short f2bf(float x) {
    union { float f; unsigned u; } v; v.f = x;   // RNE float->bf16
    return (unsigned short)((v.u + 0x7FFFu + ((v.u >> 16) & 1u)) >> 16);
}
__device__ __forceinline__ unsigned pk2bf(float a, float b) {   // v_cvt_pk_bf16_f32
    __hip_bfloat162 h = __float22bfloat162_rn(float2{a, b});
    union { __hip_bfloat162 h2; unsigned u; } cv; cv.h2 = h;
    return cv.u;
}
__device__ __forceinline__ float fexp2(float x) {   // raw v_exp_f32: D = 2^S0
    float r; asm("v_exp_f32 %0, %1" : "=v"(r) : "v"(x)); return r;
}

// ---------------- W transpose + bf16 convert: Wt[640][1024] ----------------
__global__ __launch_bounds__(256) void wtrans_kernel(
    const float* __restrict__ Wq, const float* __restrict__ Wk,
    const float* __restrict__ Wv, unsigned short* __restrict__ Wt) {
    int tid = blockIdx.x * 256 + threadIdx.x;   // 640*1024 total
    int k = tid & 1023, n = tid >> 10;
    float v;
    if (n < 256)      v = Wq[k * 256 + n];
    else if (n < 512) v = Wk[k * 256 + (n - 256)];
    else              v = Wv[k * 128 + (n - 512)];
    Wt[tid] = f2bf(v);
}

// ---------------- QKV projection GEMM (fp32 X, verified) ----------------
__global__ __launch_bounds__(256) void proj_kernel(
    const float* __restrict__ X, const unsigned short* __restrict__ Wt,
    const float* __restrict__ bq, const float* __restrict__ bk,
    const float* __restrict__ bv,
    unsigned short* __restrict__ Qs, unsigned short* __restrict__ Kb,
    unsigned short* __restrict__ Vb) {
    __shared__ alignas(16) char lds[16384];
    const int nt = blockIdx.y;
    const int m0 = blockIdx.x * 128;
    const int t = threadIdx.x, w = t >> 6, l = t & 63, c = l & 15, g = l >> 4;
    const int wm = w >> 1, wn = w & 1;
    const unsigned short* Wrow = Wt + (long)(nt * 128) * 1024;

    f32x4 acc[4][4];
    const f32x4 fz = {0.f, 0.f, 0.f, 0.f};
#pragma unroll
    for (int i = 0; i < 4; i++)
#pragma unroll
        for (int j = 0; j < 4; j++) acc[i][j] = fz;

    const int srow = t >> 1, sh = t & 1;
    const int sswz = (srow & 7) << 4;
    for (int k0 = 0; k0 < 1024; k0 += 32) {
        const float* xs = X + (long)(m0 + srow) * 1024 + k0 + sh * 16;
        float4 f0 = *(const float4*)(xs + 0);
        float4 f1 = *(const float4*)(xs + 4);
        float4 f2 = *(const float4*)(xs + 8);
        float4 f3 = *(const float4*)(xs + 12);
        const unsigned short* wsc = Wrow + (long)srow * 1024 + k0 + sh * 16;
        uint4 w0 = *(const uint4*)(wsc + 0);
        uint4 w1 = *(const uint4*)(wsc + 8);
        uint4 xa, xb;
        xa.x = pk2bf(f0.x, f0.y); xa.y = pk2bf(f0.z, f0.w);
        xa.z = pk2bf(f1.x, f1.y); xa.w = pk2bf(f1.z, f1.w);
        xb.x = pk2bf(f2.x, f2.y); xb.y = pk2bf(f2.z, f2.w);
        xb.z = pk2bf(f3.x, f3.y); xb.w = pk2bf(f3.z, f3.w);
        int base = srow * 64 + sh * 32;
        *(uint4*)(lds + ((base + 0) ^ sswz)) = xa;
        *(uint4*)(lds + ((base + 16) ^ sswz)) = xb;
        *(uint4*)(lds + 8192 + ((base + 0) ^ sswz)) = w0;
        *(uint4*)(lds + 8192 + ((base + 16) ^ sswz)) = w1;
        __syncthreads();

        bf16x8 af[4];
#pragma unroll
        for (int am = 0; am < 4; am++) {
            int r_ = wm * 64 + am * 16 + c;
            af[am] = *(const bf16x8*)(lds + ((r_ * 64 + g * 16) ^ ((c & 7) << 4)));
        }
#pragma unroll
        for (int bn = 0; bn < 4; bn++) {
            int r_ = wn * 64 + bn * 16 + c;
            bf16x8 bfr = *(const bf16x8*)(lds + 8192 + ((r_ * 64 + g * 16) ^ ((c & 7) << 4)));
#pragma unroll
            for (int am = 0; am < 4; am++) acc[am][bn] = MFMA16(af[am], bfr, acc[am][bn]);
        }
        __syncthreads();
    }

    // Q scale folds 1/sqrt(128) AND log2(e) so attn softmax is pure exp2.
    const float QSCALE = 0.08838834764831845f * 1.4426950408889634f;
    const float* bias; float scale; unsigned short* outp; int ostride, ocol0, boff;
    if (nt < 2)      { bias = bq; boff = nt * 128;       scale = QSCALE; outp = Qs; ostride = 256; ocol0 = nt * 128; }
    else if (nt < 4) { bias = bk; boff = (nt - 2) * 128; scale = 1.0f;   outp = Kb; ostride = 256; ocol0 = (nt - 2) * 128; }
    else             { bias = bv; boff = 0;              scale = 1.0f;   outp = Vb; ostride = 128; ocol0 = 0; }
#pragma unroll
    for (int bn = 0; bn < 4; bn++) {
        int ncol = wn * 64 + bn * 16 + c;
        float bb = bias[boff + ncol];
#pragma unroll
        for (int am = 0; am < 4; am++) {
#pragma unroll
            for (int r = 0; r < 4; r++) {
                long row = m0 + wm * 64 + am * 16 + 4 * g + r;
                outp[row * ostride + ocol0 + ncol] = f2bf((acc[am][bn][r] + bb) * scale);
            }
        }
    }
}

// ---------------- V transpose (LDS-tiled): Vt[b][128][4096] ------------
__global__ __launch_bounds__(256) void vtrans_kernel(
    const unsigned short* __restrict__ Vb, unsigned short* __restrict__ Vt) {
    __shared__ unsigned short lds[64][72];
    const int bid = blockIdx.x;            // 4 b x 64 sb x 2 db = 512
    const int db = bid & 1, sb = (bid >> 1) & 63, b = bid >> 7;
    const int s0 = sb * 64, d0 = db * 64;
    const int t = threadIdx.x;
    const int r = t >> 2, c4 = t & 3;
    const unsigned short* src = Vb + ((long)(b * 4096 + s0 + r)) * 128 + d0;
    uint4 u0 = *(const uint4*)(src + c4 * 8);
    uint4 u1 = *(const uint4*)(src + (c4 + 4) * 8);
    *(uint4*)(&lds[r][c4 * 8]) = u0;
    *(uint4*)(&lds[r][(c4 + 4) * 8]) = u1;
    __syncthreads();
    const int dd = t >> 2;
    unsigned short* dst = Vt + ((long)(b * 128 + d0 + dd)) * 4096 + s0;
#pragma unroll
    for (int cc2 = 0; cc2 < 2; cc2++) {
        int cc = c4 + cc2 * 4;
        unsigned short tmp[8];
#pragma unroll
        for (int j = 0; j < 8; j++) tmp[j] = lds[cc * 8 + j][dd];
        *(uint4*)(dst + cc * 8) = *(const uint4*)tmp;
    }
}

// ---------------- flash diff-attention v8.1 (KVBLK=64, fixed) -------------
// 256 threads = 4 waves x 32q, ONE branch per block (br = block coord).
// LDS: 2 buffers x 32KB {K_br[64][256B] rot @0 | V0[128][64B] @16384 |
// V1 @24576}. Stage(i+1) at top of iter i -> full-iter flight time.
__global__ __launch_bounds__(256, 2) void attn3_kernel(
    const unsigned short* __restrict__ Qs, const unsigned short* __restrict__ Kb,
    const unsigned short* __restrict__ Vt,
    float* __restrict__ Po, float* __restrict__ Ps, int nsplit, int ks) {
    __shared__ alignas(16) char lds[65536];
    const int t = threadIdx.x;
    const int w = t >> 6, l = t & 63, r31 = l & 31, hi = l >> 5;

    const int total = gridDim.x;                 // 256*nsplit (div by 8)
    const int lin = (blockIdx.x & 7) * (total >> 3) + (blockIdx.x >> 3);
    const int qb = lin & 31;
    const int g2 = lin >> 5;                     // (b*nsplit+split)*2 + br
    const int br = g2 & 1;
    const int sp = g2 >> 1;
    const int split = sp % nsplit, b = sp / nsplit;

    const long qrow = (long)b * 4096 + qb * 128 + w * 32 + r31;
    bf16x8 qf[8];
    const unsigned short* Qp = Qs + qrow * 256 + br * 128 + hi * 8;
#pragma unroll
    for (int ds = 0; ds < 8; ds++) qf[ds] = *(const bf16x8*)(Qp + ds * 16);

    f32x16 o[4];
    const f32x16 oz = {};
#pragma unroll
    for (int dt = 0; dt < 4; dt++) o[dt] = oz;
    float m = -1e30f, s = 0.f;

    // --- staging geometry: linear LDS dest (t*16), pre-rotated source ---
    const int krowA = t >> 4;                      // K rows (call j: +16j)
    const int kcolS = (((t & 15) * 16) - krowA * 16) & 255;
    const int vdA = t >> 2;                        // V d (call B: +64)
    const int vcolS = (((t & 3) * 16) - (((vdA >> 1) & 3) * 16)) & 63;
    const long kbb = (long)b * 4096;
    const char* kSrc0 = (const char*)Kb + (kbb + krowA) * 512 + br * 256 + kcolS;
    const char* vSrc0 = (const char*)Vt + ((long)b * 128 + vdA) * 8192 + vcolS;
    char* dst0 = lds + w * 1024;                   // wave-uniform base

    const int kb0 = split * ks;
    const int nt = ks >> 6;                        // 64-key tiles
#define STAGE(KB_, BUF_)                                                       \
    {                                                                          \
        const char* kp_ = kSrc0 + (long)(KB_)*512;                             \
        const char* vp_ = vSrc0 + (long)(KB_)*2;                               \
        char* d_ = dst0 + (BUF_)*32768;                                        \
        GLOAD16(kp_, d_);                                                      \
        GLOAD16(kp_ + 8192, d_ + 4096);                                        \
        GLOAD16(kp_ + 16384, d_ + 8192);                                       \
        GLOAD16(kp_ + 24576, d_ + 12288);                                      \
        GLOAD16(vp_, d_ + 16384);                                              \
        GLOAD16(vp_ + 524288, d_ + 20480);                                     \
        GLOAD16(vp_ + 64, d_ + 24576);                                         \
        GLOAD16(vp_ + 524288 + 64, d_ + 28672);                                \
    }

    // --- read offsets (loop-invariant); half1 K rows at +8192, V1 at +8192 ---
    int kro[8];
#pragma unroll
    for (int ds = 0; ds < 8; ds++)
        kro[ds] = r31 * 256 + ((ds * 32 + hi * 16 + r31 * 16) & 255);
    int vro0[4], vro1[4];
#pragma unroll
    for (int dt = 0; dt < 4; dt++) {
        int vr = dt * 32 + r31, rot = ((vr >> 1) & 3) * 16;
        vro0[dt] = 16384 + vr * 64 + ((hi * 16 + rot) & 63);
        vro1[dt] = 16384 + vr * 64 + ((32 + hi * 16 + rot) & 63);
    }

    STAGE(kb0, 0);

    for (int it = 0; it < nt; it++) {
        asm volatile("s_waitcnt vmcnt(0)" ::: "memory");
        __builtin_amdgcn_sched_barrier(0);
        __builtin_amdgcn_s_barrier();
        __builtin_amdgcn_sched_barrier(0);
        if (it + 1 < nt) STAGE(kb0 + ((it + 1) << 6), (it + 1) & 1);
        const char* bufp = lds + (it & 1) * 32768;

        // ---- QK^T both 32-key halves (4 independent 4-deep chains) ----
        f32x16 pa0 = oz, pb0_ = oz, pa1 = oz, pb1_ = oz;
        __builtin_amdgcn_s_setprio(1);
#pragma unroll
        for (int ds = 0; ds < 4; ds++) {
            bf16x8 k0a = *(const bf16x8*)(bufp + kro[ds]);
            bf16x8 k0b = *(const bf16x8*)(bufp + kro[ds + 4]);
            bf16x8 k1a = *(const bf16x8*)(bufp + 8192 + kro[ds]);
            bf16x8 k1b = *(const bf16x8*)(bufp + 8192 + kro[ds + 4]);
            pa0 = MFMA32(k0a, qf[ds], pa0);
            pb0_ = MFMA32(k0b, qf[ds + 4], pb0_);
            pa1 = MFMA32(k1a, qf[ds], pa1);
            pb1_ = MFMA32(k1b, qf[ds + 4], pb1_);
        }
        __builtin_amdgcn_s_setprio(0);
        f32x16 p0, p1;
#pragma unroll
        for (int i = 0; i < 16; i++) { p0[i] = pa0[i] + pb0_[i]; p1[i] = pa1[i] + pb1_[i]; }

        // ---- softmax over 64 keys (exp2 domain; defer-max THR=8) ----
        float x0 = fmaxf(fmaxf(p0[0], p0[1]), fmaxf(p0[2], p0[3]));
        float x1 = fmaxf(fmaxf(p0[4], p0[5]), fmaxf(p0[6], p0[7]));
        float x2 = fmaxf(fmaxf(p0[8], p0[9]), fmaxf(p0[10], p0[11]));
        float x3 = fmaxf(fmaxf(p0[12], p0[13]), fmaxf(p0[14], p0[15]));
        float y0 = fmaxf(fmaxf(p1[0], p1[1]), fmaxf(p1[2], p1[3]));
        float y1 = fmaxf(fmaxf(p1[4], p1[5]), fmaxf(p1[6], p1[7]));
        float y2 = fmaxf(fmaxf(p1[8], p1[9]), fmaxf(p1[10], p1[11]));
        float y3 = fmaxf(fmaxf(p1[12], p1[13]), fmaxf(p1[14], p1[15]));
        float lmx = fmaxf(fmaxf(fmaxf(x0, x1), fmaxf(x2, x3)),
                          fmaxf(fmaxf(y0, y1), fmaxf(y2, y3)));
        lmx = fmaxf(lmx, __shfl_xor(lmx, 32));
        if (__any(lmx > m + 8.f)) {
            float mn = fmaxf(m, lmx);
            float al = fexp2(m - mn);
            s *= al; m = mn;
#pragma unroll
            for (int dt = 0; dt < 4; dt++) o[dt] *= al;
        }
        float pe0[16], pe1[16];
#pragma unroll
        for (int i = 0; i < 16; i++) { pe0[i] = fexp2(p0[i] - m); pe1[i] = fexp2(p1[i] - m); }
        float s0 = ((pe0[0] + pe0[1]) + (pe0[2] + pe0[3])) +
                   ((pe0[4] + pe0[5]) + (pe0[6] + pe0[7]));
        float s1 = ((pe0[8] + pe0[9]) + (pe0[10] + pe0[11])) +
                   ((pe0[12] + pe0[13]) + (pe0[14] + pe0[15]));
        float s2 = ((pe1[0] + pe1[1]) + (pe1[2] + pe1[3])) +
                   ((pe1[4] + pe1[5]) + (pe1[6] + pe1[7]));
        float s3 = ((pe1[8] + pe1[9]) + (pe1[10] + pe1[11])) +
                   ((pe1[12] + pe1[13]) + (pe1[14] + pe1[15]));
        float ps_ = (s0 + s1) + (s2 + s3);
        ps_ += __shfl_xor(ps_, 32);
        s += ps_;

        // ---- P -> PV B-fragments (cvt_pk + permlane32_swap) ----
        unsigned cA = pk2bf(pe0[0], pe0[1]), cB = pk2bf(pe0[2], pe0[3]);
        unsigned cC = pk2bf(pe0[4], pe0[5]), cD = pk2bf(pe0[6], pe0[7]);
        asm volatile("v_permlane32_swap_b32 %0, %1" : "+v"(cA), "+v"(cC));
        asm volatile("v_permlane32_swap_b32 %0, %1" : "+v"(cB), "+v"(cD));
        unsigned dA = pk2bf(pe0[8], pe0[9]), dB = pk2bf(pe0[10], pe0[11]);
        unsigned dC = pk2bf(pe0[12], pe0[13]), dD = pk2bf(pe0[14], pe0[15]);
        asm volatile("v_permlane32_swap_b32 %0, %1" : "+v"(dA), "+v"(dC));
        asm volatile("v_permlane32_swap_b32 %0, %1" : "+v"(dB), "+v"(dD));
        unsigned eA = pk2bf(pe1[0], pe1[1]), eB = pk2bf(pe1[2], pe1[3]);
        unsigned eC = pk2bf(pe1[4], pe1[5]), eD = pk2bf(pe1[6], pe1[7]);
        asm volatile("v_permlane32_swap_b32 %0, %1" : "+v"(eA), "+v"(eC));
        asm volatile("v_permlane32_swap_b32 %0, %1" : "+v"(eB), "+v"(eD));
        unsigned fA = pk2bf(pe1[8], pe1[9]), fB = pk2bf(pe1[10], pe1[11]);
        unsigned fC = pk2bf(pe1[12], pe1[13]), fD = pk2bf(pe1[14], pe1[15]);
        asm volatile("v_permlane32_swap_b32 %0, %1" : "+v"(fA), "+v"(fC));
        asm volatile("v_permlane32_swap_b32 %0, %1" : "+v"(fB), "+v"(fD));
        union { uint4 u; bf16x8 v; } q00, q01, q10, q11;
        q00.u = uint4{cA, cB, cC, cD};   // keys  0-15
        q01.u = uint4{dA, dB, dC, dD};   // keys 16-31
        q10.u = uint4{eA, eB, eC, eD};   // keys 32-47
        q11.u = uint4{fA, fB, fC, fD};   // keys 48-63

        // ---- PV: O^T[d][q] += V^T-frag x PB (both halves) ----
        __builtin_amdgcn_s_setprio(1);
#pragma unroll
        for (int dt = 0; dt < 4; dt++) {
            bf16x8 v00 = *(const bf16x8*)(bufp + vro0[dt]);
            bf16x8 v01 = *(const bf16x8*)(bufp + vro1[dt]);
            bf16x8 v10 = *(const bf16x8*)(bufp + 8192 + vro0[dt]);
            bf16x8 v11 = *(const bf16x8*)(bufp + 8192 + vro1[dt]);
            o[dt] = MFMA32(v00, q00.v, o[dt]);
            o[dt] = MFMA32(v01, q01.v, o[dt]);
            o[dt] = MFMA32(v10, q10.v, o[dt]);
            o[dt] = MFMA32(v11, q11.v, o[dt]);
        }
        __builtin_amdgcn_s_setprio(0);
    }

    // ---- epilogue: per-branch partials ----
    float* po = Po + ((qrow * nsplit + split) * 2 + br) * 128;
#pragma unroll
    for (int dt = 0; dt < 4; dt++) {
#pragma unroll
        for (int rg = 0; rg < 4; rg++) {
            float4 v;   // d = dt*32 + rg*8 + hi*4 + j
            v.x = o[dt][rg * 4 + 0];
            v.y = o[dt][rg * 4 + 1];
            v.z = o[dt][rg * 4 + 2];
            v.w = o[dt][rg * 4 + 3];
            *(float4*)(po + dt * 32 + rg * 8 + hi * 4) = v;
        }
    }
    if (hi == 0)
        *(float2*)(Ps + (qrow * nsplit + split) * 4 + br * 2) = float2{m, s};
#undef STAGE
}

// ---------------- split combine ----------------
__global__ __launch_bounds__(256) void combine_kernel(
    const float* __restrict__ Po, const float* __restrict__ Ps,
    const float* __restrict__ lam_p, float* __restrict__ out, int nsplit) {
    int tid = blockIdx.x * 256 + threadIdx.x;   // 16384 q * 32 threads
    int q = tid >> 5, dq = (tid & 31) * 4;
    float M1 = -1e30f, M2 = -1e30f;
    for (int s = 0; s < nsplit; s++) {
        float4 st = *(const float4*)(Ps + (long)(q * nsplit + s) * 4);
        M1 = fmaxf(M1, st.x); M2 = fmaxf(M2, st.z);
    }
    float S1 = 0.f, S2 = 0.f;
    float a0 = 0.f, a1 = 0.f, a2 = 0.f, a3 = 0.f;
    float b0 = 0.f, b1 = 0.f, b2 = 0.f, b3 = 0.f;
    for (int s = 0; s < nsplit; s++) {
        float4 st = *(const float4*)(Ps + (long)(q * nsplit + s) * 4);
        float w1 = fexp2(st.x - M1), w2 = fexp2(st.z - M2);
        S1 += st.y * w1; S2 += st.w * w2;
        const float* p1 = Po + (((long)q * nsplit + s) * 2 + 0) * 128 + dq;
        const float* p2 = Po + (((long)q * nsplit + s) * 2 + 1) * 128 + dq;
        float4 v1 = *(const float4*)p1;
        float4 v2 = *(const float4*)p2;
        a0 += v1.x * w1; a1 += v1.y * w1; a2 += v1.z * w1; a3 += v1.w * w1;
        b0 += v2.x * w2; b1 += v2.y * w2; b2 += v2.z * w2; b3 += v2.w * w2;
    }
    float lam = *lam_p;
    float i1 = 1.f / S1, i2 = lam / S2;
    float4 v;
    v.x = a0 * i1 - b0 * i2;
    v.y = a1 * i1 - b1 * i2;
    v.z = a2 * i1 - b2 * i2;
    v.w = a3 * i1 - b3 * i2;
    *(float4*)(out + (long)q * 128 + dq) = v;
}

extern "C" void kernel_launch(void* const* d_in, const int* in_sizes, int n_in,
                              void* d_out, int out_size, void* d_ws, size_t ws_size,
                              hipStream_t stream) {
    const float* X   = (const float*)d_in[0];
    const float* lam = (const float*)d_in[1];
    const float* Wq  = (const float*)d_in[2];
    const float* bq  = (const float*)d_in[3];
    const float* Wk  = (const float*)d_in[4];
    const float* bk  = (const float*)d_in[5];
    const float* Wv  = (const float*)d_in[6];
    const float* bv  = (const float*)d_in[7];
    char* ws = (char*)d_ws;
    // ws: Qs 8M | Kb 8M | Vb 4M | Vt 4M | Wt 1.25M | @26M: Po, Ps
    unsigned short* Qs = (unsigned short*)(ws);
    unsigned short* Kb = (unsigned short*)(ws + (8u << 20));
    unsigned short* Vb = (unsigned short*)(ws + (16u << 20));
    unsigned short* Vt = (unsigned short*)(ws + (20u << 20));
    unsigned short* Wt = (unsigned short*)(ws + (24u << 20));
    const size_t base = (size_t)26 << 20;
    const size_t NQ = 16384;
    int nsplit = 1;
    if (ws_size >= base + NQ * 4 * 2 * 128 * 4 + NQ * 4 * 4 * 4)      nsplit = 4;
    else if (ws_size >= base + NQ * 2 * 2 * 128 * 4 + NQ * 2 * 4 * 4) nsplit = 2;
    float* Po = (float*)(ws + base);
    float* Ps = (float*)(ws + base + NQ * (size_t)nsplit * 2 * 128 * 4);

    wtrans_kernel<<<2560, 256, 0, stream>>>(Wq, Wk, Wv, Wt);
    proj_kernel<<<dim3(128, 5), 256, 0, stream>>>(X, Wt, bq, bk, bv, Qs, Kb, Vb);
    vtrans_kernel<<<512, 256, 0, stream>>>(Vb, Vt);
    attn3_kernel<<<256 * nsplit, 256, 0, stream>>>(Qs, Kb, Vt, Po, Ps,
                                                   nsplit, 4096 / nsplit);
    combine_kernel<<<2048, 256, 0, stream>>>(Po, Ps, lam, (float*)d_out, nsplit);
}